// Round 1
// baseline (627.394 us; speedup 1.0000x reference)
//
#include <hip/hip_runtime.h>
#include <stdint.h>

#define NROWS 64
#define DCOLS 802816
#define NTOT  51380224u
#define NBLK  784          // stats blocks; each covers 1024 columns
#define BCOLS 1024

// ---------------- Threefry-2x32, 20 rounds, key = (0, 42) -------------------
__device__ __forceinline__ void threefry2x32_k42(uint32_t x0, uint32_t x1,
                                                 uint32_t& r0, uint32_t& r1) {
  const uint32_t ks0 = 0u, ks1 = 42u, ks2 = 0x1BD11BF0u; // 0^42^0x1BD11BDA
  x0 += ks0; x1 += ks1;
#define TF_ROT(v, r) (((v) << (r)) | ((v) >> (32 - (r))))
#define TF_RND(r) { x0 += x1; x1 = TF_ROT(x1, r); x1 ^= x0; }
  TF_RND(13) TF_RND(15) TF_RND(26) TF_RND(6)
  x0 += ks1; x1 += ks2 + 1u;
  TF_RND(17) TF_RND(29) TF_RND(16) TF_RND(24)
  x0 += ks2; x1 += ks0 + 2u;
  TF_RND(13) TF_RND(15) TF_RND(26) TF_RND(6)
  x0 += ks0; x1 += ks1 + 3u;
  TF_RND(17) TF_RND(29) TF_RND(16) TF_RND(24)
  x0 += ks1; x1 += ks2 + 4u;
  TF_RND(13) TF_RND(15) TF_RND(26) TF_RND(6)
  x0 += ks2; x1 += ks0 + 5u;
  r0 = x0; r1 = x1;
#undef TF_RND
#undef TF_ROT
}

// ---------------- K1: Gram(64x64) + row sums + per-row histograms -----------
__global__ __launch_bounds__(256) void k_stats(const float* __restrict__ x,
                                               float* __restrict__ gpart,
                                               double* __restrict__ rpart,
                                               int* __restrict__ hpart) {
  __shared__ float tile[64 * 128];   // 32 KiB, XOR-swizzled 16B chunks
  __shared__ int   hist[64 * 33];    // padded stride 33 -> banks spread
  const int t = threadIdx.x;
  const int b = blockIdx.x;
  for (int o = t; o < 64 * 33; o += 256) hist[o] = 0;

  float acc[8][8];
#pragma unroll
  for (int a = 0; a < 8; a++)
#pragma unroll
    for (int c = 0; c < 8; c++) acc[a][c] = 0.f;
  double rowsum = 0.0;

  const int kq = t >> 6;      // 0..3  (k-quarter, one wave each)
  const int ti = t & 7;       // A-tile index (rows a*8+ti)
  const int tj = (t >> 3) & 7;// B-tile index (rows c*8+tj)
  const int sg = t & 31;      // staging chunk
  const int rowgrp = t >> 5;  // staging row group

  for (int sl = 0; sl < 8; ++sl) {
    __syncthreads();
    const float* src = x + (size_t)b * BCOLS + (size_t)sl * 128;
#pragma unroll
    for (int rr = 0; rr < 8; ++rr) {
      const int row = rr * 8 + rowgrp;
      const float4 v = *(const float4*)(src + (size_t)row * DCOLS + sg * 4);
      atomicAdd(&hist[row * 33 + min(max((int)rintf(v.x) + 16, 0), 31)], 1);
      atomicAdd(&hist[row * 33 + min(max((int)rintf(v.y) + 16, 0), 31)], 1);
      atomicAdd(&hist[row * 33 + min(max((int)rintf(v.z) + 16, 0), 31)], 1);
      atomicAdd(&hist[row * 33 + min(max((int)rintf(v.w) + 16, 0), 31)], 1);
      *(float4*)(&tile[row * 128 + ((sg ^ (row & 7)) << 2)]) = v;
    }
    __syncthreads();
    if (t < 64) { // exact f64 row sums (our-side precision only)
      const int r7 = t & 7;
      double rs = 0.0;
      for (int g = 0; g < 32; ++g) {
        const float4 v = *(const float4*)(&tile[t * 128 + ((g ^ r7) << 2)]);
        rs += ((double)v.x + (double)v.y) + ((double)v.z + (double)v.w);
      }
      rowsum += rs;
    }
    for (int kk = 0; kk < 8; ++kk) {
      const int g = kq * 8 + kk;
      float4 av[8], bv[8];
#pragma unroll
      for (int a = 0; a < 8; a++)
        av[a] = *(const float4*)(&tile[(a * 8 + ti) * 128 + ((g ^ ti) << 2)]);
#pragma unroll
      for (int c = 0; c < 8; c++)
        bv[c] = *(const float4*)(&tile[(c * 8 + tj) * 128 + ((g ^ tj) << 2)]);
#pragma unroll
      for (int a = 0; a < 8; a++)
#pragma unroll
        for (int c = 0; c < 8; c++)
          acc[a][c] += av[a].x * bv[c].x + av[a].y * bv[c].y +
                       av[a].z * bv[c].z + av[a].w * bv[c].w;
    }
  }
  // pairwise combine of the 4 k-quarters through LDS (tile reused: 8192 floats)
  const int tiled = ti + 8 * tj;
  __syncthreads();
  if (kq & 1) {
#pragma unroll
    for (int a = 0; a < 8; a++)
#pragma unroll
      for (int c = 0; c < 8; c++)
        tile[(kq >> 1) * 4096 + tiled * 64 + a * 8 + c] = acc[a][c];
  }
  __syncthreads();
  if (!(kq & 1)) {
#pragma unroll
    for (int a = 0; a < 8; a++)
#pragma unroll
      for (int c = 0; c < 8; c++)
        acc[a][c] += tile[(kq >> 1) * 4096 + tiled * 64 + a * 8 + c];
  }
  __syncthreads();
  if (kq == 2) {
#pragma unroll
    for (int a = 0; a < 8; a++)
#pragma unroll
      for (int c = 0; c < 8; c++)
        tile[tiled * 64 + a * 8 + c] = acc[a][c];
  }
  __syncthreads();
  if (kq == 0) {
    float* gp = gpart + (size_t)b * 4096 + tiled * 64;
#pragma unroll
    for (int a = 0; a < 8; a++)
#pragma unroll
      for (int c = 0; c < 8; c++)
        gp[a * 8 + c] = acc[a][c] + tile[tiled * 64 + a * 8 + c];
  }
  if (t < 64) rpart[(size_t)b * 64 + t] = rowsum;
  for (int o = t; o < 2048; o += 256)
    hpart[(size_t)b * 2048 + o] = hist[(o >> 5) * 33 + (o & 31)];
}

// ---------------- K2: reduce per-block partials ------------------------------
__global__ void k_reduce(const float* __restrict__ gpart,
                         const double* __restrict__ rpart,
                         const int* __restrict__ hpart,
                         double* __restrict__ G, double* __restrict__ S,
                         int* __restrict__ HIST) {
  const int o = blockIdx.x * 256 + threadIdx.x;
  if (o < 4096) {
    double acc = 0;
    for (int b = 0; b < NBLK; b++) acc += (double)gpart[(size_t)b * 4096 + o];
    const int tileIdx = o >> 6, e = o & 63;
    const int ti = tileIdx & 7, tj = tileIdx >> 3, a = e >> 3, c = e & 7;
    G[(a * 8 + ti) * 64 + (c * 8 + tj)] = acc;
  } else if (o < 4160) {
    const int r = o - 4096;
    double acc = 0;
    for (int b = 0; b < NBLK; b++) acc += rpart[(size_t)b * 64 + r];
    S[r] = acc;
  } else if (o < 6208) {
    const int h = o - 4160;
    int acc = 0;
    for (int b = 0; b < NBLK; b++) acc += hpart[(size_t)b * 2048 + h];
    HIST[h] = acc;
  }
}

// ---------------- K3: replicate the f32 factor chain -> thresholds ----------
__global__ void k_finalize(const double* __restrict__ G,
                           const double* __restrict__ S,
                           const int* __restrict__ HIST,
                           unsigned* __restrict__ mth, float* __restrict__ scl) {
#pragma clang fp contract(off)
  __shared__ double sp_sh[64];
  __shared__ float rm_sh[64];
  __shared__ float p_sh[64];
  const int i = threadIdx.x; // 64 threads
  const double invD = 1.0 / 802816.0;
  const double Si = S[i];
  // factor1 = mean |corr| over row i (f32 elementwise ops like the reference)
  const float di = (float)(G[i * 64 + i] - Si * Si * invD);
  float f1sum = 0.0f;
  for (int j = 0; j < 64; j++) {
    const double Sj = S[j];
    const float c = (float)(G[i * 64 + j] - Si * Sj * invD);
    const float dj = (float)(G[j * 64 + j] - Sj * Sj * invD);
    const float r = c / sqrtf(di * dj);
    f1sum = f1sum + fabsf(r);
  }
  const float f1 = f1sum / 64.0f;
  // row_mse from Gram identity (f64 truth, rounded to f32)
  double sp = 0;
  for (int j = 0; j < 64; j++) sp += G[i * 64 + j];
  sp_sh[i] = sp; __syncthreads();
  double T = 0;
  for (int j = 0; j < 64; j++) T += sp_sh[j];
  const double rm = (G[i * 64 + i] - sp * (2.0 / 64.0) + T * (1.0 / 4096.0)) * invD;
  rm_sh[i] = (float)rm; __syncthreads();
  float tot = 0.f;
  for (int j = 0; j < 64; j++) tot = tot + rm_sh[j];
  const float f2 = rm_sh[i] / tot;
  // entropies of rounded values; replicate jnp.log2 = log(x)/log(2f) in f32.
  // Batch bin-0 count (~19.7M) saturates at 2^24 in the reference's f32
  // segment_sum of ones -> replicate min(c, 16777216).
  const float LN2F = 0.69314718055994530942f;
  float Hb = 0.f;
  for (int k = 0; k < 32; k++) {
    int c = 0;
    for (int r = 0; r < 64; r++) c += HIST[r * 32 + k];
    if (c > 0) {
      const float cf = (float)(c > 16777216 ? 16777216 : c);
      const float pk = cf / 51380224.0f;
      const float lg = (float)log((double)pk) / LN2F;
      Hb = Hb + pk * lg;
    }
  }
  Hb = -Hb;
  float Hr = 0.f;
  for (int k = 0; k < 32; k++) {
    const int c = HIST[i * 32 + k];
    if (c > 0) {
      const float pk = ((float)c) / 802816.0f;
      const float lg = (float)log((double)pk) / LN2F;
      Hr = Hr + pk * lg;
    }
  }
  Hr = -Hr;
  const float ratio = Hr / Hb;
  const float f3 = fminf(ratio, 1.0f / ratio);
  const float p = ((1.0f - f1) * f2) * f3;
  p_sh[i] = p; __syncthreads();
  // u > p  <=>  (bits>>9) > floor(p * 2^23)   (u = m*2^-23 exactly)
  mth[i] = (unsigned)floor((double)p * 8388608.0);
  if (i == 0) {
    const float scale = 1.0f - p_sh[63];
    scl[0] = (float)(1.0 / (double)scale);
  }
}

// ---------------- K4: mask + rescale (partitionable threefry) ----------------
__global__ __launch_bounds__(256) void k_mask(const float* __restrict__ x,
                                              float* __restrict__ out,
                                              const unsigned* __restrict__ mth,
                                              const float* __restrict__ scl) {
  const float s = scl[0];
  const unsigned base = ((unsigned)blockIdx.x * 256u + threadIdx.x) * 4u;
  const float4 v = *(const float4*)(x + base);
  float res[4];
  const float vv[4] = {v.x, v.y, v.z, v.w};
#pragma unroll
  for (int e = 0; e < 4; e++) {
    const unsigned idx = base + (unsigned)e;
    const unsigned row = idx / (unsigned)DCOLS;  // compiler magic-div
    uint32_t r0, r1;
    threefry2x32_k42(0u, idx, r0, r1);           // counter = (hi=0, lo=idx)
    const uint32_t bits = r0 ^ r1;               // partitionable 32-bit join
    const bool keep = (bits >> 9) > mth[row];
    res[e] = keep ? vv[e] * s : 0.0f;
  }
  float4 o; o.x = res[0]; o.y = res[1]; o.z = res[2]; o.w = res[3];
  *(float4*)(out + base) = o;
}

extern "C" void kernel_launch(void* const* d_in, const int* in_sizes, int n_in,
                              void* d_out, int out_size, void* d_ws, size_t ws_size,
                              hipStream_t stream) {
  const float* x = (const float*)d_in[0];
  float* out = (float*)d_out;
  char* ws = (char*)d_ws;
  // ws layout (~19.7 MB total)
  float*  gpart = (float*)(ws);                    // 784*4096*4 = 12,845,056
  double* rpart = (double*)(ws + 12845056);        // 784*64*8   =    401,408
  int*    hpart = (int*)(ws + 13246464);           // 784*2048*4 =  6,422,528
  double* G     = (double*)(ws + 19668992);        // 4096*8
  double* S     = (double*)(ws + 19701760);        // 64*8
  int*    HIST  = (int*)(ws + 19702272);           // 2048*4
  unsigned* MTH = (unsigned*)(ws + 19710464);      // 64*4
  float*  SCL   = (float*)(ws + 19710720);         // 4

  k_stats<<<NBLK, 256, 0, stream>>>(x, gpart, rpart, hpart);
  k_reduce<<<25, 256, 0, stream>>>(gpart, rpart, hpart, G, S, HIST);
  k_finalize<<<1, 64, 0, stream>>>(G, S, HIST, MTH, SCL);
  k_mask<<<NTOT / 1024u, 256, 0, stream>>>(x, out, MTH, SCL);
}

// Round 2
// 578.084 us; speedup vs baseline: 1.0853x; 1.0853x over previous
//
#include <hip/hip_runtime.h>
#include <stdint.h>

#define NROWS 64
#define DCOLS 802816
#define NTOT  51380224u
#define NBLK  784          // stats blocks; each covers 1024 columns
#define BCOLS 1024

// ---------------- Threefry-2x32, 20 rounds, key = (0, 42) -------------------
__device__ __forceinline__ void threefry2x32_k42(uint32_t x0, uint32_t x1,
                                                 uint32_t& r0, uint32_t& r1) {
  const uint32_t ks0 = 0u, ks1 = 42u, ks2 = 0x1BD11BF0u; // 0^42^0x1BD11BDA
  x0 += ks0; x1 += ks1;
#define TF_ROT(v, r) (((v) << (r)) | ((v) >> (32 - (r))))
#define TF_RND(r) { x0 += x1; x1 = TF_ROT(x1, r); x1 ^= x0; }
  TF_RND(13) TF_RND(15) TF_RND(26) TF_RND(6)
  x0 += ks1; x1 += ks2 + 1u;
  TF_RND(17) TF_RND(29) TF_RND(16) TF_RND(24)
  x0 += ks2; x1 += ks0 + 2u;
  TF_RND(13) TF_RND(15) TF_RND(26) TF_RND(6)
  x0 += ks0; x1 += ks1 + 3u;
  TF_RND(17) TF_RND(29) TF_RND(16) TF_RND(24)
  x0 += ks1; x1 += ks2 + 4u;
  TF_RND(13) TF_RND(15) TF_RND(26) TF_RND(6)
  x0 += ks2; x1 += ks0 + 5u;
  r0 = x0; r1 = x1;
#undef TF_RND
#undef TF_ROT
}

// ---------------- K1: Gram(64x64) + row sums + per-row histograms -----------
// Per block: 64 rows x 1024 cols. Register-double-buffered staging; histogram
// built from staged registers into 4 lane-replicas (cuts same-address atomic
// serialization ~24 -> ~3); f32 per-thread row partials (precision slack
// proven: S perturbs corr at ~1e-13, thresholds have ~1e-3 slack in p*2^23).
__global__ __launch_bounds__(256) void k_stats(const float* __restrict__ x,
                                               float* __restrict__ gpart,
                                               float* __restrict__ rpart,
                                               int* __restrict__ hpart) {
  __shared__ float tile[64 * 128];   // 32 KiB, XOR-swizzled 16B chunks
  __shared__ int   hist[64 * 64];    // [row][bin(16)][rep(4)] = 16 KiB
  __shared__ float rsumLDS[64];
  const int t = threadIdx.x;
  const int b = blockIdx.x;
  for (int o = t; o < 4096; o += 256) hist[o] = 0;
  if (t < 64) rsumLDS[t] = 0.f;

  float acc[8][8];
#pragma unroll
  for (int a = 0; a < 8; a++)
#pragma unroll
    for (int c = 0; c < 8; c++) acc[a][c] = 0.f;
  float rsum[8] = {0.f, 0.f, 0.f, 0.f, 0.f, 0.f, 0.f, 0.f};

  const int kq = t >> 6;      // 0..3  (k-quarter, one wave each)
  const int ti = t & 7;       // A-tile index (rows a*8+ti)
  const int tj = (t >> 3) & 7;// B-tile index (rows c*8+tj)
  const int sg = t & 31;      // staging chunk
  const int rowgrp = t >> 5;  // staging row group
  const int rep = sg & 3;     // histogram replica

  const float* srcbase = x + (size_t)b * BCOLS;
  float4 R[8];
#pragma unroll
  for (int rr = 0; rr < 8; rr++) {
    const int row = rr * 8 + rowgrp;
    R[rr] = *(const float4*)(srcbase + (size_t)row * DCOLS + sg * 4);
  }

  for (int sl = 0; sl < 8; ++sl) {
    __syncthreads();  // previous Gram done; tile writable
#pragma unroll
    for (int rr = 0; rr < 8; rr++) {
      const int row = rr * 8 + rowgrp;
      *(float4*)(&tile[row * 128 + ((sg ^ (row & 7)) << 2)]) = R[rr];
    }
    // histogram + row partial sums from the registers (no LDS re-read)
#pragma unroll
    for (int rr = 0; rr < 8; rr++) {
      const int row = rr * 8 + rowgrp;
      const float4 v = R[rr];
      rsum[rr] += (v.x + v.y) + (v.z + v.w);
      int* hrow = &hist[row << 6];
      atomicAdd(&hrow[(min(max((int)rintf(v.x) + 8, 0), 15) << 2) + rep], 1);
      atomicAdd(&hrow[(min(max((int)rintf(v.y) + 8, 0), 15) << 2) + rep], 1);
      atomicAdd(&hrow[(min(max((int)rintf(v.z) + 8, 0), 15) << 2) + rep], 1);
      atomicAdd(&hrow[(min(max((int)rintf(v.w) + 8, 0), 15) << 2) + rep], 1);
    }
    // prefetch next slice; latency hidden by the Gram section below
    if (sl < 7) {
      const float* src = srcbase + (size_t)(sl + 1) * 128;
#pragma unroll
      for (int rr = 0; rr < 8; rr++) {
        const int row = rr * 8 + rowgrp;
        R[rr] = *(const float4*)(src + (size_t)row * DCOLS + sg * 4);
      }
    }
    __syncthreads();  // tile ready
    for (int kk = 0; kk < 8; ++kk) {
      const int g = kq * 8 + kk;
      float4 av[8], bv[8];
#pragma unroll
      for (int a = 0; a < 8; a++)
        av[a] = *(const float4*)(&tile[(a * 8 + ti) * 128 + ((g ^ ti) << 2)]);
#pragma unroll
      for (int c = 0; c < 8; c++)
        bv[c] = *(const float4*)(&tile[(c * 8 + tj) * 128 + ((g ^ tj) << 2)]);
#pragma unroll
      for (int a = 0; a < 8; a++)
#pragma unroll
        for (int c = 0; c < 8; c++)
          acc[a][c] += av[a].x * bv[c].x + av[a].y * bv[c].y +
                       av[a].z * bv[c].z + av[a].w * bv[c].w;
    }
  }
  // row-sum partial reduce (once per block; serialization negligible)
#pragma unroll
  for (int rr = 0; rr < 8; rr++)
    atomicAdd(&rsumLDS[rr * 8 + rowgrp], rsum[rr]);

  // pairwise combine of the 4 k-quarters through LDS (tile reused)
  const int tiled = ti + 8 * tj;
  __syncthreads();
  if (kq & 1) {
#pragma unroll
    for (int a = 0; a < 8; a++)
#pragma unroll
      for (int c = 0; c < 8; c++)
        tile[(kq >> 1) * 4096 + tiled * 64 + a * 8 + c] = acc[a][c];
  }
  __syncthreads();
  if (!(kq & 1)) {
#pragma unroll
    for (int a = 0; a < 8; a++)
#pragma unroll
      for (int c = 0; c < 8; c++)
        acc[a][c] += tile[(kq >> 1) * 4096 + tiled * 64 + a * 8 + c];
  }
  __syncthreads();
  if (kq == 2) {
#pragma unroll
    for (int a = 0; a < 8; a++)
#pragma unroll
      for (int c = 0; c < 8; c++)
        tile[tiled * 64 + a * 8 + c] = acc[a][c];
  }
  __syncthreads();
  if (kq == 0) {
    float* gp = gpart + (size_t)b * 4096 + tiled * 64;
#pragma unroll
    for (int a = 0; a < 8; a++)
#pragma unroll
      for (int c = 0; c < 8; c++)
        gp[a * 8 + c] = acc[a][c] + tile[tiled * 64 + a * 8 + c];
  }
  if (t < 64) rpart[(size_t)b * 64 + t] = rsumLDS[t];
  for (int o = t; o < 1024; o += 256) {
    const int* h = &hist[((o >> 4) << 6) + ((o & 15) << 2)];
    hpart[(size_t)b * 1024 + o] = (h[0] + h[1]) + (h[2] + h[3]);
  }
}

// ---------------- K2: reduce per-block partials (parallel, deterministic) ---
// 81 blocks x 256: 64 outputs/block x 4-way input split; coalesced over o.
__global__ __launch_bounds__(256) void k_reduce(const float* __restrict__ gpart,
                                                const float* __restrict__ rpart,
                                                const int* __restrict__ hpart,
                                                double* __restrict__ G,
                                                double* __restrict__ S,
                                                int* __restrict__ HIST) {
  __shared__ double red[4][64];
  const int t = threadIdx.x;
  const int ol = t & 63, q = t >> 6;
  const int o = blockIdx.x * 64 + ol;
  double acc = 0.0;
  if (o < 4096) {
    for (int i = 0; i < 196; i++)
      acc += (double)gpart[(size_t)(q * 196 + i) * 4096 + o];
  } else if (o < 4160) {
    const int r = o - 4096;
    for (int i = 0; i < 196; i++)
      acc += (double)rpart[(size_t)(q * 196 + i) * 64 + r];
  } else {
    const int h = o - 4160;
    long long ia = 0;
    for (int i = 0; i < 196; i++)
      ia += hpart[(size_t)(q * 196 + i) * 1024 + h];
    acc = (double)ia;  // counts < 2^31: exact in f64
  }
  red[q][ol] = acc;
  __syncthreads();
  if (q == 0) {
    const double tot = ((red[0][ol] + red[1][ol]) + red[2][ol]) + red[3][ol];
    if (o < 4096) {
      const int tileIdx = o >> 6, e = o & 63;
      const int ti = tileIdx & 7, tj = tileIdx >> 3, a = e >> 3, c = e & 7;
      G[(a * 8 + ti) * 64 + (c * 8 + tj)] = tot;
    } else if (o < 4160) {
      S[o - 4096] = tot;
    } else {
      HIST[o - 4160] = (int)tot;
    }
  }
}

// ---------------- K3: replicate the f32 factor chain -> thresholds ----------
__global__ void k_finalize(const double* __restrict__ G,
                           const double* __restrict__ S,
                           const int* __restrict__ HIST,
                           unsigned* __restrict__ mth, float* __restrict__ scl) {
#pragma clang fp contract(off)
  __shared__ double sp_sh[64];
  __shared__ float rm_sh[64];
  __shared__ float p_sh[64];
  const int i = threadIdx.x; // 64 threads
  const double invD = 1.0 / 802816.0;
  const double Si = S[i];
  // factor1 = mean |corr| over row i (f32 elementwise ops like the reference)
  const float di = (float)(G[i * 64 + i] - Si * Si * invD);
  float f1sum = 0.0f;
  for (int j = 0; j < 64; j++) {
    const double Sj = S[j];
    const float c = (float)(G[i * 64 + j] - Si * Sj * invD);
    const float dj = (float)(G[j * 64 + j] - Sj * Sj * invD);
    const float r = c / sqrtf(di * dj);
    f1sum = f1sum + fabsf(r);
  }
  const float f1 = f1sum / 64.0f;
  // row_mse from Gram identity (f64 truth, rounded to f32)
  double sp = 0;
  for (int j = 0; j < 64; j++) sp += G[i * 64 + j];
  sp_sh[i] = sp; __syncthreads();
  double T = 0;
  for (int j = 0; j < 64; j++) T += sp_sh[j];
  const double rm = (G[i * 64 + i] - sp * (2.0 / 64.0) + T * (1.0 / 4096.0)) * invD;
  rm_sh[i] = (float)rm; __syncthreads();
  float tot = 0.f;
  for (int j = 0; j < 64; j++) tot = tot + rm_sh[j];
  const float f2 = rm_sh[i] / tot;
  // entropies of rounded values; replicate jnp.log2 = log(x)/log(2f) in f32.
  // Batch bin count (~19.7M at 0) saturates at 2^24 in the reference's f32
  // segment_sum of ones -> replicate min(c, 16777216). Ascending-bin order
  // matches the reference's sorted-unique order.
  const float LN2F = 0.69314718055994530942f;
  float Hb = 0.f;
  for (int k = 0; k < 16; k++) {
    int c = 0;
    for (int r = 0; r < 64; r++) c += HIST[r * 16 + k];
    if (c > 0) {
      const float cf = (float)(c > 16777216 ? 16777216 : c);
      const float pk = cf / 51380224.0f;
      const float lg = (float)log((double)pk) / LN2F;
      Hb = Hb + pk * lg;
    }
  }
  Hb = -Hb;
  float Hr = 0.f;
  for (int k = 0; k < 16; k++) {
    const int c = HIST[i * 16 + k];
    if (c > 0) {
      const float pk = ((float)c) / 802816.0f;
      const float lg = (float)log((double)pk) / LN2F;
      Hr = Hr + pk * lg;
    }
  }
  Hr = -Hr;
  const float ratio = Hr / Hb;
  const float f3 = fminf(ratio, 1.0f / ratio);
  const float p = ((1.0f - f1) * f2) * f3;
  p_sh[i] = p; __syncthreads();
  // u > p  <=>  (bits>>9) > floor(p * 2^23)   (u = m*2^-23 exactly)
  mth[i] = (unsigned)floor((double)p * 8388608.0);
  if (i == 0) {
    const float scale = 1.0f - p_sh[63];
    scl[0] = (float)(1.0 / (double)scale);
  }
}

// ---------------- K4: mask + rescale (partitionable threefry) ----------------
__global__ __launch_bounds__(256) void k_mask(const float* __restrict__ x,
                                              float* __restrict__ out,
                                              const unsigned* __restrict__ mth,
                                              const float* __restrict__ scl) {
  const float s = scl[0];
  const unsigned base = ((unsigned)blockIdx.x * 256u + threadIdx.x) * 4u;
  const unsigned row = base / (unsigned)DCOLS;  // all 4 elems share a row
  const unsigned th = mth[row];
  const float4 v = *(const float4*)(x + base);
  float res[4];
  const float vv[4] = {v.x, v.y, v.z, v.w};
#pragma unroll
  for (int e = 0; e < 4; e++) {
    const unsigned idx = base + (unsigned)e;
    uint32_t r0, r1;
    threefry2x32_k42(0u, idx, r0, r1);           // counter = (hi=0, lo=idx)
    const uint32_t bits = r0 ^ r1;               // partitionable 32-bit join
    const bool keep = (bits >> 9) > th;
    res[e] = keep ? vv[e] * s : 0.0f;
  }
  float4 o; o.x = res[0]; o.y = res[1]; o.z = res[2]; o.w = res[3];
  *(float4*)(out + base) = o;
}

extern "C" void kernel_launch(void* const* d_in, const int* in_sizes, int n_in,
                              void* d_out, int out_size, void* d_ws, size_t ws_size,
                              hipStream_t stream) {
  const float* x = (const float*)d_in[0];
  float* out = (float*)d_out;
  char* ws = (char*)d_ws;
  // ws layout (~16.3 MB total)
  float*  gpart = (float*)(ws);                    // 784*4096*4 = 12,845,056
  float*  rpart = (float*)(ws + 12845056);         // 784*64*4   =    200,704
  int*    hpart = (int*)(ws + 13045760);           // 784*1024*4 =  3,211,264
  double* G     = (double*)(ws + 16257024);        // 4096*8
  double* S     = (double*)(ws + 16289792);        // 64*8
  int*    HIST  = (int*)(ws + 16290304);           // 1024*4
  unsigned* MTH = (unsigned*)(ws + 16294400);      // 64*4
  float*  SCL   = (float*)(ws + 16294656);         // 4

  k_stats<<<NBLK, 256, 0, stream>>>(x, gpart, rpart, hpart);
  k_reduce<<<81, 256, 0, stream>>>(gpart, rpart, hpart, G, S, HIST);
  k_finalize<<<1, 64, 0, stream>>>(G, S, HIST, MTH, SCL);
  k_mask<<<NTOT / 1024u, 256, 0, stream>>>(x, out, MTH, SCL);
}

// Round 3
// 484.015 us; speedup vs baseline: 1.2962x; 1.1944x over previous
//
#include <hip/hip_runtime.h>
#include <stdint.h>

#define NROWS 64
#define DCOLS 802816
#define NTOT  51380224u
#define NBLK  784          // stats blocks; each covers 1024 columns
#define BCOLS 1024
#define NSLICE 8           // 128-col slices

typedef short short8v __attribute__((ext_vector_type(8)));
typedef float f32x4 __attribute__((ext_vector_type(4)));

// ---------------- Threefry-2x32, 20 rounds, key = (0, 42) -------------------
__device__ __forceinline__ void threefry2x32_k42(uint32_t x0, uint32_t x1,
                                                 uint32_t& r0, uint32_t& r1) {
  const uint32_t ks0 = 0u, ks1 = 42u, ks2 = 0x1BD11BF0u; // 0^42^0x1BD11BDA
  x0 += ks0; x1 += ks1;
#define TF_ROT(v, r) (((v) << (r)) | ((v) >> (32 - (r))))
#define TF_RND(r) { x0 += x1; x1 = TF_ROT(x1, r); x1 ^= x0; }
  TF_RND(13) TF_RND(15) TF_RND(26) TF_RND(6)
  x0 += ks1; x1 += ks2 + 1u;
  TF_RND(17) TF_RND(29) TF_RND(16) TF_RND(24)
  x0 += ks2; x1 += ks0 + 2u;
  TF_RND(13) TF_RND(15) TF_RND(26) TF_RND(6)
  x0 += ks0; x1 += ks1 + 3u;
  TF_RND(17) TF_RND(29) TF_RND(16) TF_RND(24)
  x0 += ks1; x1 += ks2 + 4u;
  TF_RND(13) TF_RND(15) TF_RND(26) TF_RND(6)
  x0 += ks2; x1 += ks0 + 5u;
  r0 = x0; r1 = x1;
#undef TF_RND
#undef TF_ROT
}

__device__ __forceinline__ uint32_t bf16_rne(float x) {
  const uint32_t u = __float_as_uint(x);
  return (u + 0x7FFFu + ((u >> 16) & 1u)) >> 16;
}

// ---------------- K1: MFMA Gram(64x64) + row sums + histograms --------------
// Gram via 4-term bf16 split: X=H+L, X.X^T = HH^T+HL^T+LH^T+LL^T; f32 MFMA
// accumulation == precision class of the previous f32-FMA chain (passed at
// absmax 0). A.A^T: A-frag and B-frag share the identical lane->(row,k) map,
// so both operands are plain swizzled ds_read_b128 of row tiles.
__global__ __launch_bounds__(256) void k_stats(const float* __restrict__ x,
                                               float* __restrict__ gpart,
                                               float* __restrict__ rpart,
                                               int* __restrict__ hpart) {
  __shared__ short Ht[64 * 128];   // 16 KiB, XOR-swizzled 16B chunks
  __shared__ short Lt[64 * 128];   // 16 KiB
  __shared__ int   hist[64 * 64];  // [row][bin16][rep4] = 16 KiB
  __shared__ float rsumLDS[64];
  const int t = threadIdx.x;
  const int b = blockIdx.x;
  for (int o = t; o < 4096; o += 256) hist[o] = 0;
  if (t < 64) rsumLDS[t] = 0.f;

  const int w = t >> 6;        // wave 0..3
  const int lane = t & 63;
  const int i0 = (w & 1) * 2;  // this wave's 2x2 tile block of the 4x4 grid
  const int j0 = (w >> 1) * 2;
  const int sg = t & 31;       // staging chunk (float4)
  const int rowgrp = t >> 5;   // staging row group 0..7
  const int rep = t & 3;       // histogram replica

  f32x4 acc[2][2];
#pragma unroll
  for (int ui = 0; ui < 2; ui++)
#pragma unroll
    for (int uj = 0; uj < 2; uj++) acc[ui][uj] = (f32x4)0.f;
  float rsum[8] = {0.f, 0.f, 0.f, 0.f, 0.f, 0.f, 0.f, 0.f};

  const float* srcbase = x + (size_t)b * BCOLS;
  float4 R[8];
#pragma unroll
  for (int rr = 0; rr < 8; rr++) {
    const int row = rr * 8 + rowgrp;
    R[rr] = *(const float4*)(srcbase + (size_t)row * DCOLS + sg * 4);
  }

  for (int sl = 0; sl < NSLICE; ++sl) {
    __syncthreads();  // previous slice's MFMA reads done; tiles writable
#pragma unroll
    for (int rr = 0; rr < 8; rr++) {
      const int row = rr * 8 + rowgrp;
      const float4 v = R[rr];
      rsum[rr] += (v.x + v.y) + (v.z + v.w);
      int* hrow = &hist[row << 6];
      atomicAdd(&hrow[(min(max((int)rintf(v.x) + 8, 0), 15) << 2) + rep], 1);
      atomicAdd(&hrow[(min(max((int)rintf(v.y) + 8, 0), 15) << 2) + rep], 1);
      atomicAdd(&hrow[(min(max((int)rintf(v.z) + 8, 0), 15) << 2) + rep], 1);
      atomicAdd(&hrow[(min(max((int)rintf(v.w) + 8, 0), 15) << 2) + rep], 1);
      // bf16 hi/lo split (RNE); x ~= hi + lo to ~17 mantissa bits
      const uint32_t hx = bf16_rne(v.x), hy = bf16_rne(v.y);
      const uint32_t hz = bf16_rne(v.z), hw = bf16_rne(v.w);
      const uint32_t lx = bf16_rne(v.x - __uint_as_float(hx << 16));
      const uint32_t ly = bf16_rne(v.y - __uint_as_float(hy << 16));
      const uint32_t lz = bf16_rne(v.z - __uint_as_float(hz << 16));
      const uint32_t lw = bf16_rne(v.w - __uint_as_float(hw << 16));
      uint2 hp, lp;
      hp.x = hx | (hy << 16); hp.y = hz | (hw << 16);
      lp.x = lx | (ly << 16); lp.y = lz | (lw << 16);
      const int woff = row * 256 + ((((sg >> 1) ^ (row & 7)) << 4) | ((sg & 1) << 3));
      *(uint2*)((char*)Ht + woff) = hp;
      *(uint2*)((char*)Lt + woff) = lp;
    }
    if (sl + 1 < NSLICE) {  // register prefetch; hides under MFMA phase
      const float* src = srcbase + (size_t)(sl + 1) * 128;
#pragma unroll
      for (int rr = 0; rr < 8; rr++) {
        const int row = rr * 8 + rowgrp;
        R[rr] = *(const float4*)(src + (size_t)row * DCOLS + sg * 4);
      }
    }
    __syncthreads();  // tiles ready
#pragma unroll
    for (int ks = 0; ks < 4; ks++) {
      const int kc = ks * 4 + (lane >> 4);  // 16B chunk index 0..15
      short8v aH[2], aL[2], bH[2], bL[2];
#pragma unroll
      for (int u = 0; u < 2; u++) {
        const int ar = (i0 + u) * 16 + (lane & 15);
        const int aoff = ar * 256 + ((kc ^ (ar & 7)) << 4);
        aH[u] = *(short8v*)((char*)Ht + aoff);
        aL[u] = *(short8v*)((char*)Lt + aoff);
        const int br = (j0 + u) * 16 + (lane & 15);
        const int boff = br * 256 + ((kc ^ (br & 7)) << 4);
        bH[u] = *(short8v*)((char*)Ht + boff);
        bL[u] = *(short8v*)((char*)Lt + boff);
      }
#pragma unroll
      for (int ui = 0; ui < 2; ui++)
#pragma unroll
        for (int uj = 0; uj < 2; uj++) {
          acc[ui][uj] = __builtin_amdgcn_mfma_f32_16x16x32_bf16(aH[ui], bH[uj], acc[ui][uj], 0, 0, 0);
          acc[ui][uj] = __builtin_amdgcn_mfma_f32_16x16x32_bf16(aH[ui], bL[uj], acc[ui][uj], 0, 0, 0);
          acc[ui][uj] = __builtin_amdgcn_mfma_f32_16x16x32_bf16(aL[ui], bH[uj], acc[ui][uj], 0, 0, 0);
          acc[ui][uj] = __builtin_amdgcn_mfma_f32_16x16x32_bf16(aL[ui], bL[uj], acc[ui][uj], 0, 0, 0);
        }
    }
  }
  // row-sum partial reduce (order = lane order; deterministic, proven in R2)
#pragma unroll
  for (int rr = 0; rr < 8; rr++)
    atomicAdd(&rsumLDS[rr * 8 + rowgrp], rsum[rr]);

  // gpart in natural (i*64+j) order; C/D map: col=lane&15, row=(lane>>4)*4+r
  float* gp = gpart + (size_t)b * 4096;
#pragma unroll
  for (int ui = 0; ui < 2; ui++)
#pragma unroll
    for (int uj = 0; uj < 2; uj++)
#pragma unroll
      for (int r = 0; r < 4; r++) {
        const int grow = (i0 + ui) * 16 + (lane >> 4) * 4 + r;
        const int gcol = (j0 + uj) * 16 + (lane & 15);
        gp[grow * 64 + gcol] = acc[ui][uj][r];
      }
  __syncthreads();
  if (t < 64) rpart[(size_t)b * 64 + t] = rsumLDS[t];
  for (int o = t; o < 1024; o += 256) {
    const int* h = &hist[((o >> 4) << 6) + ((o & 15) << 2)];
    hpart[(size_t)b * 1024 + o] = (h[0] + h[1]) + (h[2] + h[3]);
  }
}

// ---------------- K2: reduce per-block partials (parallel, deterministic) ---
__global__ __launch_bounds__(256) void k_reduce(const float* __restrict__ gpart,
                                                const float* __restrict__ rpart,
                                                const int* __restrict__ hpart,
                                                double* __restrict__ G,
                                                double* __restrict__ S,
                                                int* __restrict__ HIST) {
  __shared__ double red[4][64];
  const int t = threadIdx.x;
  const int ol = t & 63, q = t >> 6;
  const int o = blockIdx.x * 64 + ol;
  double acc = 0.0;
  if (o < 4096) {
    for (int i = 0; i < 196; i++)
      acc += (double)gpart[(size_t)(q * 196 + i) * 4096 + o];
  } else if (o < 4160) {
    const int r = o - 4096;
    for (int i = 0; i < 196; i++)
      acc += (double)rpart[(size_t)(q * 196 + i) * 64 + r];
  } else {
    const int h = o - 4160;
    long long ia = 0;
    for (int i = 0; i < 196; i++)
      ia += hpart[(size_t)(q * 196 + i) * 1024 + h];
    acc = (double)ia;  // counts < 2^31: exact in f64
  }
  red[q][ol] = acc;
  __syncthreads();
  if (q == 0) {
    const double tot = ((red[0][ol] + red[1][ol]) + red[2][ol]) + red[3][ol];
    if (o < 4096) {
      G[o] = tot;
    } else if (o < 4160) {
      S[o - 4096] = tot;
    } else {
      HIST[o - 4160] = (int)tot;
    }
  }
}

// ---------------- K3: replicate the f32 factor chain -> thresholds ----------
__global__ void k_finalize(const double* __restrict__ G,
                           const double* __restrict__ S,
                           const int* __restrict__ HIST,
                           unsigned* __restrict__ mth, float* __restrict__ scl) {
#pragma clang fp contract(off)
  __shared__ double sp_sh[64];
  __shared__ float rm_sh[64];
  __shared__ float p_sh[64];
  const int i = threadIdx.x; // 64 threads
  const double invD = 1.0 / 802816.0;
  const double Si = S[i];
  // factor1 = mean |corr| over row i (f32 elementwise ops like the reference)
  const float di = (float)(G[i * 64 + i] - Si * Si * invD);
  float f1sum = 0.0f;
  for (int j = 0; j < 64; j++) {
    const double Sj = S[j];
    const float c = (float)(G[i * 64 + j] - Si * Sj * invD);
    const float dj = (float)(G[j * 64 + j] - Sj * Sj * invD);
    const float r = c / sqrtf(di * dj);
    f1sum = f1sum + fabsf(r);
  }
  const float f1 = f1sum / 64.0f;
  // row_mse from Gram identity (f64 truth, rounded to f32)
  double sp = 0;
  for (int j = 0; j < 64; j++) sp += G[i * 64 + j];
  sp_sh[i] = sp; __syncthreads();
  double T = 0;
  for (int j = 0; j < 64; j++) T += sp_sh[j];
  const double rm = (G[i * 64 + i] - sp * (2.0 / 64.0) + T * (1.0 / 4096.0)) * invD;
  rm_sh[i] = (float)rm; __syncthreads();
  float tot = 0.f;
  for (int j = 0; j < 64; j++) tot = tot + rm_sh[j];
  const float f2 = rm_sh[i] / tot;
  // entropies of rounded values; replicate jnp.log2 = log(x)/log(2f) in f32.
  // Batch bin count (~19.7M at 0) saturates at 2^24 in the reference's f32
  // segment_sum of ones -> replicate min(c, 16777216).
  const float LN2F = 0.69314718055994530942f;
  float Hb = 0.f;
  for (int k = 0; k < 16; k++) {
    int c = 0;
    for (int r = 0; r < 64; r++) c += HIST[r * 16 + k];
    if (c > 0) {
      const float cf = (float)(c > 16777216 ? 16777216 : c);
      const float pk = cf / 51380224.0f;
      const float lg = (float)log((double)pk) / LN2F;
      Hb = Hb + pk * lg;
    }
  }
  Hb = -Hb;
  float Hr = 0.f;
  for (int k = 0; k < 16; k++) {
    const int c = HIST[i * 16 + k];
    if (c > 0) {
      const float pk = ((float)c) / 802816.0f;
      const float lg = (float)log((double)pk) / LN2F;
      Hr = Hr + pk * lg;
    }
  }
  Hr = -Hr;
  const float ratio = Hr / Hb;
  const float f3 = fminf(ratio, 1.0f / ratio);
  const float p = ((1.0f - f1) * f2) * f3;
  p_sh[i] = p; __syncthreads();
  // u > p  <=>  (bits>>9) > floor(p * 2^23)   (u = m*2^-23 exactly)
  mth[i] = (unsigned)floor((double)p * 8388608.0);
  if (i == 0) {
    const float scale = 1.0f - p_sh[63];
    scl[0] = (float)(1.0 / (double)scale);
  }
}

// ---------------- K4: mask + rescale (partitionable threefry) ----------------
__global__ __launch_bounds__(256) void k_mask(const float* __restrict__ x,
                                              float* __restrict__ out,
                                              const unsigned* __restrict__ mth,
                                              const float* __restrict__ scl) {
  const float s = scl[0];
  const unsigned base = ((unsigned)blockIdx.x * 256u + threadIdx.x) * 4u;
  const unsigned row = base / (unsigned)DCOLS;  // all 4 elems share a row
  const unsigned th = mth[row];
  const float4 v = *(const float4*)(x + base);
  float res[4];
  const float vv[4] = {v.x, v.y, v.z, v.w};
#pragma unroll
  for (int e = 0; e < 4; e++) {
    const unsigned idx = base + (unsigned)e;
    uint32_t r0, r1;
    threefry2x32_k42(0u, idx, r0, r1);           // counter = (hi=0, lo=idx)
    const uint32_t bits = r0 ^ r1;               // partitionable 32-bit join
    const bool keep = (bits >> 9) > th;
    res[e] = keep ? vv[e] * s : 0.0f;
  }
  float4 o; o.x = res[0]; o.y = res[1]; o.z = res[2]; o.w = res[3];
  *(float4*)(out + base) = o;
}

extern "C" void kernel_launch(void* const* d_in, const int* in_sizes, int n_in,
                              void* d_out, int out_size, void* d_ws, size_t ws_size,
                              hipStream_t stream) {
  const float* x = (const float*)d_in[0];
  float* out = (float*)d_out;
  char* ws = (char*)d_ws;
  // ws layout (~16.3 MB total)
  float*  gpart = (float*)(ws);                    // 784*4096*4 = 12,845,056
  float*  rpart = (float*)(ws + 12845056);         // 784*64*4   =    200,704
  int*    hpart = (int*)(ws + 13045760);           // 784*1024*4 =  3,211,264
  double* G     = (double*)(ws + 16257024);        // 4096*8
  double* S     = (double*)(ws + 16289792);        // 64*8
  int*    HIST  = (int*)(ws + 16290304);           // 1024*4
  unsigned* MTH = (unsigned*)(ws + 16294400);      // 64*4
  float*  SCL   = (float*)(ws + 16294656);         // 4

  k_stats<<<NBLK, 256, 0, stream>>>(x, gpart, rpart, hpart);
  k_reduce<<<81, 256, 0, stream>>>(gpart, rpart, hpart, G, S, HIST);
  k_finalize<<<1, 64, 0, stream>>>(G, S, HIST, MTH, SCL);
  k_mask<<<NTOT / 1024u, 256, 0, stream>>>(x, out, MTH, SCL);
}